// Round 8
// baseline (863.970 us; speedup 1.0000x reference)
//
#include <hip/hip_runtime.h>
#include <math.h>

#define NUM_LAYER 6

typedef __attribute__((ext_vector_type(8))) short short8;
typedef __attribute__((ext_vector_type(4))) float f32x4;
typedef unsigned short u16;

// Exact 3-way bf16 truncation split: x == h + m + l bit-exactly (8+8+8 bits).
__device__ __forceinline__ void split3(float x, u16& h, u16& m, u16& l) {
  unsigned ux = __float_as_uint(x);
  h = (u16)(ux >> 16);
  float r1 = x - __uint_as_float(ux & 0xFFFF0000u);
  unsigned u1 = __float_as_uint(r1);
  m = (u16)(u1 >> 16);
  float r2 = r1 - __uint_as_float(u1 & 0xFFFF0000u);
  l = (u16)(__float_as_uint(r2) >> 16);
}

// ---------------- Pass A: Q = Wq*vf + bq ; K = Wk*ef + bk ----------------
__global__ __launch_bounds__(256) void qk_gemm_split(
    const float* __restrict__ Wq, const float* __restrict__ bq,
    const float* __restrict__ vf,
    const float* __restrict__ Wk, const float* __restrict__ bk,
    const float* __restrict__ ef,
    u16* __restrict__ Qh, u16* __restrict__ Qm, u16* __restrict__ Ql,
    u16* __restrict__ Kh, u16* __restrict__ Km, u16* __restrict__ Kl,
    int C, int N, int bs) {
  int which = (int)blockIdx.y >= bs;
  int b = (int)blockIdx.y - (which ? bs : 0);
  const float* Wm = which ? Wk : Wq;
  const float* bias = which ? bk : bq;
  const float* X = (which ? ef : vf) + (size_t)b * C * N;
  u16* Ph = which ? Kh : Qh;
  u16* Pm = which ? Km : Qm;
  u16* Pl = which ? Kl : Ql;
  int n0 = blockIdx.x * 128;
  __shared__ float As[8][128];
  __shared__ float Xs[8][128];
  int t = threadIdx.x;
  int tx = t & 15, ty = t >> 4;
  int ao = t >> 1, ac = (t & 1) * 4;
  int lk = t >> 5, lj = (t & 31) * 4;
  float acc[8][8] = {};
  for (int c0 = 0; c0 < C; c0 += 8) {
    __syncthreads();
    float4 wv = *(const float4*)&Wm[(size_t)ao * C + c0 + ac];
    As[ac + 0][ao] = wv.x; As[ac + 1][ao] = wv.y;
    As[ac + 2][ao] = wv.z; As[ac + 3][ao] = wv.w;
    *(float4*)&Xs[lk][lj] = *(const float4*)&X[(size_t)(c0 + lk) * N + n0 + lj];
    __syncthreads();
#pragma unroll
    for (int kk = 0; kk < 8; ++kk) {
      float a[8], bb[8];
      *(float4*)&a[0]  = *(const float4*)&As[kk][ty * 4];
      *(float4*)&a[4]  = *(const float4*)&As[kk][64 + ty * 4];
      *(float4*)&bb[0] = *(const float4*)&Xs[kk][tx * 4];
      *(float4*)&bb[4] = *(const float4*)&Xs[kk][64 + tx * 4];
#pragma unroll
      for (int i = 0; i < 8; ++i)
#pragma unroll
        for (int j = 0; j < 8; ++j)
          acc[i][j] = fmaf(a[i], bb[j], acc[i][j]);
    }
  }
  float bv[8];
#pragma unroll
  for (int i = 0; i < 8; ++i) bv[i] = bias[(i >> 2) * 64 + ty * 4 + (i & 3)];
#pragma unroll
  for (int j = 0; j < 8; ++j) {
    int n = n0 + tx * 4 + (j & 3) + (j >> 2) * 64;
    size_t nb = ((size_t)b * N + n) * C;
#pragma unroll
    for (int g = 0; g < 2; ++g) {
      int r0 = g * 64 + ty * 4;
      ushort4 hv, mv, lv;
      split3(acc[g * 4 + 0][j] + bv[g * 4 + 0], hv.x, mv.x, lv.x);
      split3(acc[g * 4 + 1][j] + bv[g * 4 + 1], hv.y, mv.y, lv.y);
      split3(acc[g * 4 + 2][j] + bv[g * 4 + 2], hv.z, mv.z, lv.z);
      split3(acc[g * 4 + 3][j] + bv[g * 4 + 3], hv.w, mv.w, lv.w);
      *(ushort4*)&Ph[nb + r0] = hv;
      *(ushort4*)&Pm[nb + r0] = mv;
      *(ushort4*)&Pl[nb + r0] = lv;
    }
  }
}

// ---------------- Pass B: score via MFMA bf16 3-split (R7-validated) --------
// sm = u16[6][128][32] (64 B rows, all LDS ops 16B-aligned b128) with XOR slot
// swizzle slot' = slot ^ ((row>>1)&3) — conflict-free by full enumeration.
// et aliases sm (dead after K-loop). LDS 49.2 KB => 3 blocks/CU. 851 us base.
__device__ __forceinline__ int smoff(int a, int row, int slot) {
  return ((a * 128 + row) * 4 + (slot ^ ((row >> 1) & 3))) * 8;  // u16 units
}

__global__ __launch_bounds__(256) void att_mfma(
    const u16* __restrict__ Qh, const u16* __restrict__ Qm,
    const u16* __restrict__ Ql, const u16* __restrict__ Kh,
    const u16* __restrict__ Km, const u16* __restrict__ Kl,
    const float* __restrict__ H0, float* __restrict__ score,
    int C, int N, float rsdh) {
  int b = blockIdx.z;
  int o0 = blockIdx.y * 128, i0 = blockIdx.x * 128;
  __shared__ __align__(16) char smem_raw[6 * 128 * 32 * 2];  // 49152 B
  u16* smraw = (u16*)smem_raw;
  float (*et)[16][68] = (float(*)[16][68])smem_raw;  // aliased epilogue tile
  int t = threadIdx.x;
  int wave = t >> 6, lane = t & 63, quad = lane >> 4, lr = lane & 15;
  int wo = wave >> 1, wi = wave & 1;
  f32x4 acc[4][4];
#pragma unroll
  for (int mi = 0; mi < 4; ++mi)
#pragma unroll
    for (int ni = 0; ni < 4; ++ni) acc[mi][ni] = (f32x4){0.f, 0.f, 0.f, 0.f};

  int ro = t >> 1, ch = (t & 1) * 16;   // global u16 col base (0 or 16)
  int sl = (t & 1) * 2;                 // logical slot base (0 or 2)
  size_t qbase = ((size_t)b * N + o0 + ro) * C + ch;
  size_t kbase = ((size_t)b * N + i0 + ro) * C + ch;
  const u16* gq[3] = {Qh, Qm, Ql};
  const u16* gk[3] = {Kh, Km, Kl};

  for (int c0 = 0; c0 < C; c0 += 32) {
    __syncthreads();
#pragma unroll
    for (int a = 0; a < 3; ++a) {
      const uint4* src = (const uint4*)(gq[a] + qbase + c0);
      *(uint4*)&smraw[smoff(a, ro, sl)] = src[0];
      *(uint4*)&smraw[smoff(a, ro, sl + 1)] = src[1];
      const uint4* srk = (const uint4*)(gk[a] + kbase + c0);
      *(uint4*)&smraw[smoff(3 + a, ro, sl)] = srk[0];
      *(uint4*)&smraw[smoff(3 + a, ro, sl + 1)] = srk[1];
    }
    __syncthreads();
    short8 bh[4], bm[4], bl[4];
#pragma unroll
    for (int ni = 0; ni < 4; ++ni) {
      int row = wi * 64 + ni * 16 + lr;
      bh[ni] = *(const short8*)&smraw[smoff(3, row, quad)];
      bm[ni] = *(const short8*)&smraw[smoff(4, row, quad)];
      bl[ni] = *(const short8*)&smraw[smoff(5, row, quad)];
    }
#pragma unroll
    for (int mi = 0; mi < 4; ++mi) {
      int row = wo * 64 + mi * 16 + lr;
      short8 ah = *(const short8*)&smraw[smoff(0, row, quad)];
      short8 am = *(const short8*)&smraw[smoff(1, row, quad)];
      short8 al = *(const short8*)&smraw[smoff(2, row, quad)];
#pragma unroll
      for (int ni = 0; ni < 4; ++ni) {
        f32x4 c = acc[mi][ni];
        c = __builtin_amdgcn_mfma_f32_16x16x32_bf16(ah, bl[ni], c, 0, 0, 0);
        c = __builtin_amdgcn_mfma_f32_16x16x32_bf16(al, bh[ni], c, 0, 0, 0);
        c = __builtin_amdgcn_mfma_f32_16x16x32_bf16(am, bm[ni], c, 0, 0, 0);
        c = __builtin_amdgcn_mfma_f32_16x16x32_bf16(ah, bm[ni], c, 0, 0, 0);
        c = __builtin_amdgcn_mfma_f32_16x16x32_bf16(am, bh[ni], c, 0, 0, 0);
        c = __builtin_amdgcn_mfma_f32_16x16x32_bf16(ah, bh[ni], c, 0, 0, 0);
        acc[mi][ni] = c;
      }
    }
  }
  __syncthreads();  // sm dead from here; et aliases its storage
  const float* Hb = H0 + (size_t)b * N * N;
  float* Sb = score + (size_t)b * N * N;
  int rr = lane >> 2, seg = lane & 3;
#pragma unroll
  for (int mi = 0; mi < 4; ++mi) {
#pragma unroll
    for (int ni = 0; ni < 4; ++ni)
#pragma unroll
      for (int r = 0; r < 4; ++r)
        et[wave][quad * 4 + r][ni * 16 + lr] = acc[mi][ni][r];
    __syncthreads();
    int o = o0 + wo * 64 + mi * 16 + rr;
    const float* hr = Hb + (size_t)o * N + i0 + wi * 64;
    float* sr = Sb + (size_t)o * N + i0 + wi * 64;
#pragma unroll
    for (int j = 0; j < 4; ++j) {
      int col = j * 16 + seg * 4;
      float4 c = *(const float4*)&et[wave][rr][col];
      float4 h = *(const float4*)&hr[col];
      float4 oV;
      oV.x = (h.x > 0.f) ? 1.f / (1.f + __expf(-c.x * rsdh)) : 0.f;
      oV.y = (h.y > 0.f) ? 1.f / (1.f + __expf(-c.y * rsdh)) : 0.f;
      oV.z = (h.z > 0.f) ? 1.f / (1.f + __expf(-c.z * rsdh)) : 0.f;
      oV.w = (h.w > 0.f) ? 1.f / (1.f + __expf(-c.w * rsdh)) : 0.f;
      *(float4*)&sr[col] = oV;
    }
    __syncthreads();  // et reused next mi
  }
}

// ---- Pass C (fused): per-row exact k-th largest + select from registers.
// R8: bank-spread accumulator permutation. Column c is stored at
//   p(c) = (c&3)*(N/4) + (c>>2)
// so the conditional atomics of element e hit bank (lane mod 32) — uniform
// 2 lanes/bank (free) and all 32 banks active, vs the old 8-banks/8-way.
// Write-out inverts p with 4 scalar LDS reads per float4. Same summation
// sets & order per column => bit-exact.
template <int V4>
__global__ __launch_bounds__(512) void topk_select(
    float* __restrict__ scoreW, float* __restrict__ Hout,
    float* __restrict__ degV, float* __restrict__ Dv, int dodv,
    float* __restrict__ PE, float* __restrict__ PW,
    const int* __restrict__ itp, int N) {
  int b = blockIdx.y;
  int strip = blockIdx.x;
  int t = threadIdx.x;
  int wave = t >> 6, lane = t & 63;
  int row = strip * 8 + wave;
  size_t rowoff = ((size_t)b * N + row) * N;
  extern __shared__ float cols[];  // [2][N]: colE, colW (permuted layout)
  float* colE = cols;
  float* colW = cols + N;
  for (int i = t; i < 2 * N; i += 512) cols[i] = 0.f;

  float4 v4[V4];
#pragma unroll
  for (int q = 0; q < V4; ++q)
    v4[q] = *(const float4*)(scoreW + rowoff + 4 * lane + (q << 8));
  int itv = *itp;
  int k = (int)floor((double)N * 0.1 * (double)(NUM_LAYER - 1 - itv) + 0.5);
  unsigned lo = 0u, hi = 0x3F800000u;  // scores in [0, 1]
  while (lo < hi) {
    unsigned r = hi - lo;
    unsigned p1 = lo + (r + 2u) / 3u;          // >= lo+1
    unsigned p2 = lo + (2u * r + 2u) / 3u;     // p1 <= p2 <= hi
    float t1 = __uint_as_float(p1), t2 = __uint_as_float(p2);
    int c = 0;
#pragma unroll
    for (int q = 0; q < V4; ++q) {
      c += (v4[q].x >= t1) ? 1 : 0; c += (v4[q].x >= t2) ? 0x10000 : 0;
      c += (v4[q].y >= t1) ? 1 : 0; c += (v4[q].y >= t2) ? 0x10000 : 0;
      c += (v4[q].z >= t1) ? 1 : 0; c += (v4[q].z >= t2) ? 0x10000 : 0;
      c += (v4[q].w >= t1) ? 1 : 0; c += (v4[q].w >= t2) ? 0x10000 : 0;
    }
#pragma unroll
    for (int off = 1; off < 64; off <<= 1) c += __shfl_xor(c, off);
    int c2 = c >> 16, c1 = c & 0xFFFF;
    if (c2 >= k) lo = p2;
    else if (c1 >= k) { lo = p1; hi = p2 - 1u; }
    else hi = p1 - 1u;
  }
  float am = __uint_as_float(lo);  // uniform across wave
  __syncthreads();                 // cols[] zeroed

  int np4 = N >> 2;
  float rs = 0.f;
#pragma unroll
  for (int q = 0; q < V4; ++q) {
    int c0 = 4 * lane + (q << 8);
    int pi = lane + (q << 6);  // p(c0) = (c0&3)*np4 + (c0>>2), c0&3==0
    float4 s = v4[q];
    float4 w, h;
    w.x = (s.x >= am) ? s.x : 0.f; h.x = (w.x > 0.f) ? 1.f : 0.f;
    w.y = (s.y >= am) ? s.y : 0.f; h.y = (w.y > 0.f) ? 1.f : 0.f;
    w.z = (s.z >= am) ? s.z : 0.f; h.z = (w.z > 0.f) ? 1.f : 0.f;
    w.w = (s.w >= am) ? s.w : 0.f; h.w = (w.w > 0.f) ? 1.f : 0.f;
    *(float4*)(scoreW + rowoff + c0) = w;
    *(float4*)(Hout + rowoff + c0) = h;
    rs += h.x + h.y + h.z + h.w;
    if (h.x != 0.f) { atomicAdd(&colE[pi], 1.f);           atomicAdd(&colW[pi], w.x); }
    if (h.y != 0.f) { atomicAdd(&colE[np4 + pi], 1.f);     atomicAdd(&colW[np4 + pi], w.y); }
    if (h.z != 0.f) { atomicAdd(&colE[2 * np4 + pi], 1.f); atomicAdd(&colW[2 * np4 + pi], w.z); }
    if (h.w != 0.f) { atomicAdd(&colE[3 * np4 + pi], 1.f); atomicAdd(&colW[3 * np4 + pi], w.w); }
  }
#pragma unroll
  for (int off = 32; off; off >>= 1) rs += __shfl_down(rs, off);
  float rsb = __shfl(rs, 0);
  if (lane == 0) degV[b * N + row] = rsb;
  if (dodv) {
    float inv = (rsb != 0.f) ? 1.f / rsb : 0.f;
    float* dvr = Dv + ((size_t)b * N + row) * N;
    for (int c4 = lane * 4; c4 < N; c4 += 256) {
      float4 z = {0.f, 0.f, 0.f, 0.f};
      unsigned dd = (unsigned)(row - c4);
      if (dd < 4u) ((float*)&z)[dd] = inv;
      *(float4*)&dvr[c4] = z;
    }
  }
  __syncthreads();
  int S = N >> 3;
  size_t pbase = ((size_t)b * S + strip) * N;
  for (int c = 4 * t; c < N; c += 2048) {
    int r = c >> 2;
    float4 e4, w4;
    e4.x = colE[r];           w4.x = colW[r];
    e4.y = colE[np4 + r];     w4.y = colW[np4 + r];
    e4.z = colE[2 * np4 + r]; w4.z = colW[2 * np4 + r];
    e4.w = colE[3 * np4 + r]; w4.w = colW[3 * np4 + r];
    *(float4*)(PE + pbase + c) = e4;
    *(float4*)(PW + pbase + c) = w4;
  }
}

// ---------------- Pass D: reduce column partials -> degE, We ----------------
__global__ __launch_bounds__(256) void col_reduce(
    const float* __restrict__ PE, const float* __restrict__ PW,
    float* __restrict__ degE, float* __restrict__ We, int N, int S) {
  int b = blockIdx.y;
  int l = threadIdx.x & 63;
  int sg = threadIdx.x >> 6;  // 0..3
  int col = blockIdx.x * 64 + l;
  int cnt = S >> 2;
  int s0 = sg * cnt;
  float se = 0.f, sw = 0.f;
  for (int i = 0; i < cnt; ++i) {
    size_t o = ((size_t)b * S + s0 + i) * N + col;
    se += PE[o];
    sw += PW[o];
  }
  __shared__ float rE[4][64], rW[4][64];
  rE[sg][l] = se;
  rW[sg][l] = sw;
  __syncthreads();
  if (sg == 0) {
    float te = rE[0][l] + rE[1][l] + rE[2][l] + rE[3][l];
    float tw = rW[0][l] + rW[1][l] + rW[2][l] + rW[3][l];
    degE[b * N + col] = te;
    We[b * N + col] = tw;
  }
}

// ------- Pass E: streaming fill of De (and Dv in fallback path) -------
__global__ __launch_bounds__(256) void dedv_fill(
    float* __restrict__ De, float* __restrict__ Dv,
    const float* __restrict__ degE, const float* __restrict__ degV, int N) {
  int arr = blockIdx.z;
  int b = blockIdx.y;
  int r0 = blockIdx.x * 8;
  float* out = (arr ? Dv : De) + (size_t)b * N * N;
  const float* deg = (arr ? degV : degE) + b * N;
  int t = threadIdx.x;
#pragma unroll
  for (int r = r0; r < r0 + 8; ++r) {
    float d = deg[r];
    float inv = (d != 0.f) ? 1.f / d : 0.f;
    size_t rowoff = (size_t)r * N;
    for (int c4 = t * 4; c4 < N; c4 += 1024) {
      float4 v = {0.f, 0.f, 0.f, 0.f};
      unsigned dd = (unsigned)(r - c4);
      if (dd < 4u) ((float*)&v)[dd] = inv;
      *(float4*)&out[rowoff + c4] = v;
    }
  }
}

// ---------------- Pass F: W_edge normalize ----------------
__global__ __launch_bounds__(256) void wedge_norm(
    const float* __restrict__ We, float* __restrict__ out, int N) {
  int b = blockIdx.x;
  int t = threadIdx.x;
  const float* w = We + (size_t)b * N;
  float ss = 0.f;
  for (int i = t; i < N; i += 256) { float x = w[i]; ss += x * x; }
  for (int off = 32; off; off >>= 1) ss += __shfl_down(ss, off);
  __shared__ float p[4];
  if ((t & 63) == 0) p[t >> 6] = ss;
  __syncthreads();
  float tot = p[0] + p[1] + p[2] + p[3];
  float nrm = fmaxf(sqrtf(tot), 1e-12f);
  for (int i = t; i < N; i += 256) out[(size_t)b * N + i] = w[i] / nrm;
}

extern "C" void kernel_launch(void* const* d_in, const int* in_sizes, int n_in,
                              void* d_out, int out_size, void* d_ws, size_t ws_size,
                              hipStream_t stream) {
  const float* H0 = (const float*)d_in[0];
  const float* vf = (const float*)d_in[1];
  const float* ef = (const float*)d_in[2];
  const float* Wq = (const float*)d_in[3];
  const float* bq = (const float*)d_in[4];
  const float* Wk = (const float*)d_in[5];
  const float* bk = (const float*)d_in[6];
  const int* itp  = (const int*)d_in[7];

  int C = (int)(sqrt((double)in_sizes[3]) + 0.5);          // 128
  long long ratio = (long long)in_sizes[0] / in_sizes[1];  // N/C
  int N = (int)(C * ratio);                                // 2048
  int bs = (int)(in_sizes[1] / ((long long)C * N));        // 8
  size_t bNN = (size_t)bs * N * N;
  size_t bNC = (size_t)bs * N * C;
  int S = N >> 3;                                          // 8-row strips
  size_t pElems = (size_t)bs * S * N;

  float* outH  = (float*)d_out;
  float* outW  = outH + bNN;
  float* outDe = outW + bNN;
  float* outDv = outDe + bNN;
  float* outWe = outDv + bNN;

  size_t bsN = (size_t)bs * N;
  float* degE = (float*)d_ws;
  float* degV = degE + bsN;
  float* We   = degV + bsN;
  u16* splits;   // 6 arrays of bNC u16 each
  float* PE;
  float* PW;
  int dodv;  // 1: pass C writes Dv rows (real workspace). 0: fallback (PE
             // aliases outDv, so Dv must be filled after col_reduce).
  size_t need = 3 * bsN * sizeof(float) + 6 * bNC * sizeof(u16) +
                2 * pElems * sizeof(float);
  if (ws_size >= need) {
    splits = (u16*)(We + bsN);
    PE = (float*)(splits + 6 * bNC);
    PW = PE + pElems;
    dodv = 1;
  } else {
    // outDe/outDv dead until later passes — safe scratch.
    splits = (u16*)outDe;
    PE = outDv;
    PW = PE + pElems;
    dodv = 0;
  }
  u16* Qh = splits;
  u16* Qm = Qh + bNC;
  u16* Ql = Qm + bNC;
  u16* Kh = Ql + bNC;
  u16* Km = Kh + bNC;
  u16* Kl = Km + bNC;

  float rsdh = (float)(1.0 / sqrt((double)C));  // NUM_HEADS==1 -> dh=C
  size_t colsBytes = 2 * (size_t)N * sizeof(float);

  qk_gemm_split<<<dim3(N / 128, 2 * bs), 256, 0, stream>>>(
      Wq, bq, vf, Wk, bk, ef, Qh, Qm, Ql, Kh, Km, Kl, C, N, bs);
  att_mfma<<<dim3(N / 128, N / 128, bs), 256, 0, stream>>>(
      Qh, Qm, Ql, Kh, Km, Kl, H0, outW, C, N, rsdh);
  if (N == 2048)
    topk_select<8><<<dim3(S, bs), 512, colsBytes, stream>>>(
        outW, outH, degV, outDv, dodv, PE, PW, itp, N);
  else if (N == 1024)
    topk_select<4><<<dim3(S, bs), 512, colsBytes, stream>>>(
        outW, outH, degV, outDv, dodv, PE, PW, itp, N);
  else  // N == 4096
    topk_select<16><<<dim3(S, bs), 512, colsBytes, stream>>>(
        outW, outH, degV, outDv, dodv, PE, PW, itp, N);
  col_reduce<<<dim3(N / 64, bs), 256, 0, stream>>>(PE, PW, degE, We, N, S);
  // De always filled here; Dv too only in the fallback path.
  dedv_fill<<<dim3(N / 8, bs, dodv ? 1 : 2), 256, 0, stream>>>(
      outDe, outDv, degE, degV, N);
  wedge_norm<<<dim3(bs), 256, 0, stream>>>(We, outWe, N);
}

// Round 9
// 837.355 us; speedup vs baseline: 1.0318x; 1.0318x over previous
//
#include <hip/hip_runtime.h>
#include <math.h>

#define NUM_LAYER 6

typedef __attribute__((ext_vector_type(8))) short short8;
typedef __attribute__((ext_vector_type(4))) float f32x4;
typedef unsigned short u16;

// Exact 3-way bf16 truncation split: x == h + m + l bit-exactly (8+8+8 bits).
__device__ __forceinline__ void split3(float x, u16& h, u16& m, u16& l) {
  unsigned ux = __float_as_uint(x);
  h = (u16)(ux >> 16);
  float r1 = x - __uint_as_float(ux & 0xFFFF0000u);
  unsigned u1 = __float_as_uint(r1);
  m = (u16)(u1 >> 16);
  float r2 = r1 - __uint_as_float(u1 & 0xFFFF0000u);
  l = (u16)(__float_as_uint(r2) >> 16);
}

// ---------------- Pass A: Q = Wq*vf + bq ; K = Wk*ef + bk ----------------
// R9: also zero-inits the deg/We accumulators (zbuf, 3*bs*N floats) so pass C
// can accumulate columns with global atomics (replaces PE/PW + col_reduce).
__global__ __launch_bounds__(256) void qk_gemm_split(
    const float* __restrict__ Wq, const float* __restrict__ bq,
    const float* __restrict__ vf,
    const float* __restrict__ Wk, const float* __restrict__ bk,
    const float* __restrict__ ef,
    u16* __restrict__ Qh, u16* __restrict__ Qm, u16* __restrict__ Ql,
    u16* __restrict__ Kh, u16* __restrict__ Km, u16* __restrict__ Kl,
    float* __restrict__ zbuf, int zcount,
    int C, int N, int bs) {
  int t = threadIdx.x;
  {  // prologue zero-init (disjoint from A's own data; no sync needed)
    int fid = (int)blockIdx.y * gridDim.x + (int)blockIdx.x;
    int zoff = fid * 1024 + t * 4;
    if (zoff < zcount) {
      float4 z = {0.f, 0.f, 0.f, 0.f};
      *(float4*)&zbuf[zoff] = z;
    }
  }
  int which = (int)blockIdx.y >= bs;
  int b = (int)blockIdx.y - (which ? bs : 0);
  const float* Wm = which ? Wk : Wq;
  const float* bias = which ? bk : bq;
  const float* X = (which ? ef : vf) + (size_t)b * C * N;
  u16* Ph = which ? Kh : Qh;
  u16* Pm = which ? Km : Qm;
  u16* Pl = which ? Kl : Ql;
  int n0 = blockIdx.x * 128;
  __shared__ float As[8][128];
  __shared__ float Xs[8][128];
  int tx = t & 15, ty = t >> 4;
  int ao = t >> 1, ac = (t & 1) * 4;
  int lk = t >> 5, lj = (t & 31) * 4;
  float acc[8][8] = {};
  for (int c0 = 0; c0 < C; c0 += 8) {
    __syncthreads();
    float4 wv = *(const float4*)&Wm[(size_t)ao * C + c0 + ac];
    As[ac + 0][ao] = wv.x; As[ac + 1][ao] = wv.y;
    As[ac + 2][ao] = wv.z; As[ac + 3][ao] = wv.w;
    *(float4*)&Xs[lk][lj] = *(const float4*)&X[(size_t)(c0 + lk) * N + n0 + lj];
    __syncthreads();
#pragma unroll
    for (int kk = 0; kk < 8; ++kk) {
      float a[8], bb[8];
      *(float4*)&a[0]  = *(const float4*)&As[kk][ty * 4];
      *(float4*)&a[4]  = *(const float4*)&As[kk][64 + ty * 4];
      *(float4*)&bb[0] = *(const float4*)&Xs[kk][tx * 4];
      *(float4*)&bb[4] = *(const float4*)&Xs[kk][64 + tx * 4];
#pragma unroll
      for (int i = 0; i < 8; ++i)
#pragma unroll
        for (int j = 0; j < 8; ++j)
          acc[i][j] = fmaf(a[i], bb[j], acc[i][j]);
    }
  }
  float bv[8];
#pragma unroll
  for (int i = 0; i < 8; ++i) bv[i] = bias[(i >> 2) * 64 + ty * 4 + (i & 3)];
#pragma unroll
  for (int j = 0; j < 8; ++j) {
    int n = n0 + tx * 4 + (j & 3) + (j >> 2) * 64;
    size_t nb = ((size_t)b * N + n) * C;
#pragma unroll
    for (int g = 0; g < 2; ++g) {
      int r0 = g * 64 + ty * 4;
      ushort4 hv, mv, lv;
      split3(acc[g * 4 + 0][j] + bv[g * 4 + 0], hv.x, mv.x, lv.x);
      split3(acc[g * 4 + 1][j] + bv[g * 4 + 1], hv.y, mv.y, lv.y);
      split3(acc[g * 4 + 2][j] + bv[g * 4 + 2], hv.z, mv.z, lv.z);
      split3(acc[g * 4 + 3][j] + bv[g * 4 + 3], hv.w, mv.w, lv.w);
      *(ushort4*)&Ph[nb + r0] = hv;
      *(ushort4*)&Pm[nb + r0] = mv;
      *(ushort4*)&Pl[nb + r0] = lv;
    }
  }
}

// ---------------- Pass B: score via MFMA bf16 3-split (R7-validated) --------
// sm = u16[6][128][32] (64 B rows, all LDS ops 16B-aligned b128) with XOR slot
// swizzle slot' = slot ^ ((row>>1)&3) — conflict-free by full enumeration.
// et aliases sm (dead after K-loop). LDS 49.2 KB => 3 blocks/CU. 851 us base.
__device__ __forceinline__ int smoff(int a, int row, int slot) {
  return ((a * 128 + row) * 4 + (slot ^ ((row >> 1) & 3))) * 8;  // u16 units
}

__global__ __launch_bounds__(256) void att_mfma(
    const u16* __restrict__ Qh, const u16* __restrict__ Qm,
    const u16* __restrict__ Ql, const u16* __restrict__ Kh,
    const u16* __restrict__ Km, const u16* __restrict__ Kl,
    const float* __restrict__ H0, float* __restrict__ score,
    int C, int N, float rsdh) {
  int b = blockIdx.z;
  int o0 = blockIdx.y * 128, i0 = blockIdx.x * 128;
  __shared__ __align__(16) char smem_raw[6 * 128 * 32 * 2];  // 49152 B
  u16* smraw = (u16*)smem_raw;
  float (*et)[16][68] = (float(*)[16][68])smem_raw;  // aliased epilogue tile
  int t = threadIdx.x;
  int wave = t >> 6, lane = t & 63, quad = lane >> 4, lr = lane & 15;
  int wo = wave >> 1, wi = wave & 1;
  f32x4 acc[4][4];
#pragma unroll
  for (int mi = 0; mi < 4; ++mi)
#pragma unroll
    for (int ni = 0; ni < 4; ++ni) acc[mi][ni] = (f32x4){0.f, 0.f, 0.f, 0.f};

  int ro = t >> 1, ch = (t & 1) * 16;   // global u16 col base (0 or 16)
  int sl = (t & 1) * 2;                 // logical slot base (0 or 2)
  size_t qbase = ((size_t)b * N + o0 + ro) * C + ch;
  size_t kbase = ((size_t)b * N + i0 + ro) * C + ch;
  const u16* gq[3] = {Qh, Qm, Ql};
  const u16* gk[3] = {Kh, Km, Kl};

  for (int c0 = 0; c0 < C; c0 += 32) {
    __syncthreads();
#pragma unroll
    for (int a = 0; a < 3; ++a) {
      const uint4* src = (const uint4*)(gq[a] + qbase + c0);
      *(uint4*)&smraw[smoff(a, ro, sl)] = src[0];
      *(uint4*)&smraw[smoff(a, ro, sl + 1)] = src[1];
      const uint4* srk = (const uint4*)(gk[a] + kbase + c0);
      *(uint4*)&smraw[smoff(3 + a, ro, sl)] = srk[0];
      *(uint4*)&smraw[smoff(3 + a, ro, sl + 1)] = srk[1];
    }
    __syncthreads();
    short8 bh[4], bm[4], bl[4];
#pragma unroll
    for (int ni = 0; ni < 4; ++ni) {
      int row = wi * 64 + ni * 16 + lr;
      bh[ni] = *(const short8*)&smraw[smoff(3, row, quad)];
      bm[ni] = *(const short8*)&smraw[smoff(4, row, quad)];
      bl[ni] = *(const short8*)&smraw[smoff(5, row, quad)];
    }
#pragma unroll
    for (int mi = 0; mi < 4; ++mi) {
      int row = wo * 64 + mi * 16 + lr;
      short8 ah = *(const short8*)&smraw[smoff(0, row, quad)];
      short8 am = *(const short8*)&smraw[smoff(1, row, quad)];
      short8 al = *(const short8*)&smraw[smoff(2, row, quad)];
#pragma unroll
      for (int ni = 0; ni < 4; ++ni) {
        f32x4 c = acc[mi][ni];
        c = __builtin_amdgcn_mfma_f32_16x16x32_bf16(ah, bl[ni], c, 0, 0, 0);
        c = __builtin_amdgcn_mfma_f32_16x16x32_bf16(al, bh[ni], c, 0, 0, 0);
        c = __builtin_amdgcn_mfma_f32_16x16x32_bf16(am, bm[ni], c, 0, 0, 0);
        c = __builtin_amdgcn_mfma_f32_16x16x32_bf16(ah, bm[ni], c, 0, 0, 0);
        c = __builtin_amdgcn_mfma_f32_16x16x32_bf16(am, bh[ni], c, 0, 0, 0);
        c = __builtin_amdgcn_mfma_f32_16x16x32_bf16(ah, bh[ni], c, 0, 0, 0);
        acc[mi][ni] = c;
      }
    }
  }
  __syncthreads();  // sm dead from here; et aliases its storage
  const float* Hb = H0 + (size_t)b * N * N;
  float* Sb = score + (size_t)b * N * N;
  int rr = lane >> 2, seg = lane & 3;
#pragma unroll
  for (int mi = 0; mi < 4; ++mi) {
#pragma unroll
    for (int ni = 0; ni < 4; ++ni)
#pragma unroll
      for (int r = 0; r < 4; ++r)
        et[wave][quad * 4 + r][ni * 16 + lr] = acc[mi][ni][r];
    __syncthreads();
    int o = o0 + wo * 64 + mi * 16 + rr;
    const float* hr = Hb + (size_t)o * N + i0 + wi * 64;
    float* sr = Sb + (size_t)o * N + i0 + wi * 64;
#pragma unroll
    for (int j = 0; j < 4; ++j) {
      int col = j * 16 + seg * 4;
      float4 c = *(const float4*)&et[wave][rr][col];
      float4 h = *(const float4*)&hr[col];
      float4 oV;
      oV.x = (h.x > 0.f) ? 1.f / (1.f + __expf(-c.x * rsdh)) : 0.f;
      oV.y = (h.y > 0.f) ? 1.f / (1.f + __expf(-c.y * rsdh)) : 0.f;
      oV.z = (h.z > 0.f) ? 1.f / (1.f + __expf(-c.z * rsdh)) : 0.f;
      oV.w = (h.w > 0.f) ? 1.f / (1.f + __expf(-c.w * rsdh)) : 0.f;
      *(float4*)&sr[col] = oV;
    }
    __syncthreads();  // et reused next mi
  }
}

// ---- Pass C (fused): per-row exact k-th largest + select from registers.
// R7-exact core (R8's bank-spread permutation reverted: conditional atomics
// at ~10% density never conflicted meaningfully; the permuted write-out cost
// more than it saved). R9: epilogue flushes the per-strip column partials
// straight into degE/We with conditional global atomics (~57% nonzero) —
// removes the PE/PW round-trip and the col_reduce kernel entirely. Also
// always writes Dv rows here (nothing aliases outDv anymore).
template <int V4>
__global__ __launch_bounds__(512) void topk_select(
    float* __restrict__ scoreW, float* __restrict__ Hout,
    float* __restrict__ degV, float* __restrict__ Dv,
    float* __restrict__ degE, float* __restrict__ WeAcc,
    const int* __restrict__ itp, int N) {
  int b = blockIdx.y;
  int strip = blockIdx.x;
  int t = threadIdx.x;
  int wave = t >> 6, lane = t & 63;
  int row = strip * 8 + wave;
  size_t rowoff = ((size_t)b * N + row) * N;
  extern __shared__ float cols[];  // [2][N]: colE, colW
  float* colE = cols;
  float* colW = cols + N;
  for (int i = t; i < 2 * N; i += 512) cols[i] = 0.f;

  float4 v4[V4];
#pragma unroll
  for (int q = 0; q < V4; ++q)
    v4[q] = *(const float4*)(scoreW + rowoff + 4 * lane + (q << 8));
  int itv = *itp;
  int k = (int)floor((double)N * 0.1 * (double)(NUM_LAYER - 1 - itv) + 0.5);
  unsigned lo = 0u, hi = 0x3F800000u;  // scores in [0, 1]
  while (lo < hi) {
    unsigned r = hi - lo;
    unsigned p1 = lo + (r + 2u) / 3u;          // >= lo+1
    unsigned p2 = lo + (2u * r + 2u) / 3u;     // p1 <= p2 <= hi
    float t1 = __uint_as_float(p1), t2 = __uint_as_float(p2);
    int c = 0;
#pragma unroll
    for (int q = 0; q < V4; ++q) {
      c += (v4[q].x >= t1) ? 1 : 0; c += (v4[q].x >= t2) ? 0x10000 : 0;
      c += (v4[q].y >= t1) ? 1 : 0; c += (v4[q].y >= t2) ? 0x10000 : 0;
      c += (v4[q].z >= t1) ? 1 : 0; c += (v4[q].z >= t2) ? 0x10000 : 0;
      c += (v4[q].w >= t1) ? 1 : 0; c += (v4[q].w >= t2) ? 0x10000 : 0;
    }
#pragma unroll
    for (int off = 1; off < 64; off <<= 1) c += __shfl_xor(c, off);
    int c2 = c >> 16, c1 = c & 0xFFFF;
    if (c2 >= k) lo = p2;
    else if (c1 >= k) { lo = p1; hi = p2 - 1u; }
    else hi = p1 - 1u;
  }
  float am = __uint_as_float(lo);  // uniform across wave
  __syncthreads();                 // cols[] zeroed

  float rs = 0.f;
#pragma unroll
  for (int q = 0; q < V4; ++q) {
    int c0 = 4 * lane + (q << 8);
    float4 s = v4[q];
    float4 w, h;
    w.x = (s.x >= am) ? s.x : 0.f; h.x = (w.x > 0.f) ? 1.f : 0.f;
    w.y = (s.y >= am) ? s.y : 0.f; h.y = (w.y > 0.f) ? 1.f : 0.f;
    w.z = (s.z >= am) ? s.z : 0.f; h.z = (w.z > 0.f) ? 1.f : 0.f;
    w.w = (s.w >= am) ? s.w : 0.f; h.w = (w.w > 0.f) ? 1.f : 0.f;
    *(float4*)(scoreW + rowoff + c0) = w;
    *(float4*)(Hout + rowoff + c0) = h;
    rs += h.x + h.y + h.z + h.w;
    if (h.x != 0.f) { atomicAdd(&colE[c0 + 0], 1.f); atomicAdd(&colW[c0 + 0], w.x); }
    if (h.y != 0.f) { atomicAdd(&colE[c0 + 1], 1.f); atomicAdd(&colW[c0 + 1], w.y); }
    if (h.z != 0.f) { atomicAdd(&colE[c0 + 2], 1.f); atomicAdd(&colW[c0 + 2], w.z); }
    if (h.w != 0.f) { atomicAdd(&colE[c0 + 3], 1.f); atomicAdd(&colW[c0 + 3], w.w); }
  }
#pragma unroll
  for (int off = 32; off; off >>= 1) rs += __shfl_down(rs, off);
  float rsb = __shfl(rs, 0);
  if (lane == 0) degV[b * N + row] = rsb;
  {
    // fused Dv row: zeros + 1/degV on the diagonal (row owned by this wave)
    float inv = (rsb != 0.f) ? 1.f / rsb : 0.f;
    float* dvr = Dv + ((size_t)b * N + row) * N;
    for (int c4 = lane * 4; c4 < N; c4 += 256) {
      float4 z = {0.f, 0.f, 0.f, 0.f};
      unsigned dd = (unsigned)(row - c4);
      if (dd < 4u) ((float*)&z)[dd] = inv;
      *(float4*)&dvr[c4] = z;
    }
  }
  __syncthreads();
  // flush nonzero column partials with global atomics (degE exact: integer
  // counts in fp32; We reassociation ~1e-5 abs, far inside tolerance)
  for (int c = t; c < 2 * N; c += 512) {
    float v = cols[c];
    if (v != 0.f) {
      if (c < N) atomicAdd(&degE[b * N + c], v);
      else       atomicAdd(&WeAcc[b * N + c - N], v);
    }
  }
}

// ------- Pass E: streaming fill of De (zeros + 1/degE diagonal) -------
__global__ __launch_bounds__(256) void de_fill(
    float* __restrict__ De, const float* __restrict__ degE, int N) {
  int b = blockIdx.y;
  int r0 = blockIdx.x * 8;
  float* out = De + (size_t)b * N * N;
  const float* deg = degE + b * N;
  int t = threadIdx.x;
#pragma unroll
  for (int r = r0; r < r0 + 8; ++r) {
    float d = deg[r];
    float inv = (d != 0.f) ? 1.f / d : 0.f;
    size_t rowoff = (size_t)r * N;
    for (int c4 = t * 4; c4 < N; c4 += 1024) {
      float4 v = {0.f, 0.f, 0.f, 0.f};
      unsigned dd = (unsigned)(r - c4);
      if (dd < 4u) ((float*)&v)[dd] = inv;
      *(float4*)&out[rowoff + c4] = v;
    }
  }
}

// ---------------- Pass F: W_edge normalize ----------------
__global__ __launch_bounds__(256) void wedge_norm(
    const float* __restrict__ We, float* __restrict__ out, int N) {
  int b = blockIdx.x;
  int t = threadIdx.x;
  const float* w = We + (size_t)b * N;
  float ss = 0.f;
  for (int i = t; i < N; i += 256) { float x = w[i]; ss += x * x; }
  for (int off = 32; off; off >>= 1) ss += __shfl_down(ss, off);
  __shared__ float p[4];
  if ((t & 63) == 0) p[t >> 6] = ss;
  __syncthreads();
  float tot = p[0] + p[1] + p[2] + p[3];
  float nrm = fmaxf(sqrtf(tot), 1e-12f);
  for (int i = t; i < N; i += 256) out[(size_t)b * N + i] = w[i] / nrm;
}

extern "C" void kernel_launch(void* const* d_in, const int* in_sizes, int n_in,
                              void* d_out, int out_size, void* d_ws, size_t ws_size,
                              hipStream_t stream) {
  const float* H0 = (const float*)d_in[0];
  const float* vf = (const float*)d_in[1];
  const float* ef = (const float*)d_in[2];
  const float* Wq = (const float*)d_in[3];
  const float* bq = (const float*)d_in[4];
  const float* Wk = (const float*)d_in[5];
  const float* bk = (const float*)d_in[6];
  const int* itp  = (const int*)d_in[7];

  int C = (int)(sqrt((double)in_sizes[3]) + 0.5);          // 128
  long long ratio = (long long)in_sizes[0] / in_sizes[1];  // N/C
  int N = (int)(C * ratio);                                // 2048
  int bs = (int)(in_sizes[1] / ((long long)C * N));        // 8
  size_t bNN = (size_t)bs * N * N;
  size_t bNC = (size_t)bs * N * C;
  int S = N >> 3;                                          // 8-row strips

  float* outH  = (float*)d_out;
  float* outW  = outH + bNN;
  float* outDe = outW + bNN;
  float* outDv = outDe + bNN;
  float* outWe = outDv + bNN;

  size_t bsN = (size_t)bs * N;
  float* degE = (float*)d_ws;   // zero-init'd in pass A prologue
  float* degV = degE + bsN;
  float* We   = degV + bsN;
  u16* splits;   // 6 arrays of bNC u16 each
  size_t need = 3 * bsN * sizeof(float) + 6 * bNC * sizeof(u16);
  if (ws_size >= need) {
    splits = (u16*)(We + bsN);
  } else {
    // outDe dead until de_fill (after topk_select) — safe scratch.
    splits = (u16*)outDe;
  }
  u16* Qh = splits;
  u16* Qm = Qh + bNC;
  u16* Ql = Qm + bNC;
  u16* Kh = Ql + bNC;
  u16* Km = Kh + bNC;
  u16* Kl = Km + bNC;

  float rsdh = (float)(1.0 / sqrt((double)C));  // NUM_HEADS==1 -> dh=C
  size_t colsBytes = 2 * (size_t)N * sizeof(float);
  int zcount = (int)(3 * bsN);  // degE, degV, We contiguous

  qk_gemm_split<<<dim3(N / 128, 2 * bs), 256, 0, stream>>>(
      Wq, bq, vf, Wk, bk, ef, Qh, Qm, Ql, Kh, Km, Kl, degE, zcount, C, N, bs);
  att_mfma<<<dim3(N / 128, N / 128, bs), 256, 0, stream>>>(
      Qh, Qm, Ql, Kh, Km, Kl, H0, outW, C, N, rsdh);
  if (N == 2048)
    topk_select<8><<<dim3(S, bs), 512, colsBytes, stream>>>(
        outW, outH, degV, outDv, degE, We, itp, N);
  else if (N == 1024)
    topk_select<4><<<dim3(S, bs), 512, colsBytes, stream>>>(
        outW, outH, degV, outDv, degE, We, itp, N);
  else  // N == 4096
    topk_select<16><<<dim3(S, bs), 512, colsBytes, stream>>>(
        outW, outH, degV, outDv, degE, We, itp, N);
  de_fill<<<dim3(N / 8, bs), 256, 0, stream>>>(outDe, degE, N);
  wedge_norm<<<dim3(bs), 256, 0, stream>>>(We, outWe, N);
}

// Round 10
// 829.445 us; speedup vs baseline: 1.0416x; 1.0095x over previous
//
#include <hip/hip_runtime.h>
#include <math.h>

#define NUM_LAYER 6

typedef __attribute__((ext_vector_type(8))) short short8;
typedef __attribute__((ext_vector_type(4))) float f32x4;
typedef unsigned short u16;

// Exact 3-way bf16 truncation split: x == h + m + l bit-exactly (8+8+8 bits).
__device__ __forceinline__ void split3(float x, u16& h, u16& m, u16& l) {
  unsigned ux = __float_as_uint(x);
  h = (u16)(ux >> 16);
  float r1 = x - __uint_as_float(ux & 0xFFFF0000u);
  unsigned u1 = __float_as_uint(r1);
  m = (u16)(u1 >> 16);
  float r2 = r1 - __uint_as_float(u1 & 0xFFFF0000u);
  l = (u16)(__float_as_uint(r2) >> 16);
}

// ---------------- Pass A: Q = Wq*vf + bq ; K = Wk*ef + bk ----------------
// Also zero-inits the deg/We accumulators (zbuf) for pass C's global atomics.
__global__ __launch_bounds__(256) void qk_gemm_split(
    const float* __restrict__ Wq, const float* __restrict__ bq,
    const float* __restrict__ vf,
    const float* __restrict__ Wk, const float* __restrict__ bk,
    const float* __restrict__ ef,
    u16* __restrict__ Qh, u16* __restrict__ Qm, u16* __restrict__ Ql,
    u16* __restrict__ Kh, u16* __restrict__ Km, u16* __restrict__ Kl,
    float* __restrict__ zbuf, int zcount,
    int C, int N, int bs) {
  int t = threadIdx.x;
  {  // prologue zero-init (disjoint from A's own data; no sync needed)
    int fid = (int)blockIdx.y * gridDim.x + (int)blockIdx.x;
    int zoff = fid * 1024 + t * 4;
    if (zoff < zcount) {
      float4 z = {0.f, 0.f, 0.f, 0.f};
      *(float4*)&zbuf[zoff] = z;
    }
  }
  int which = (int)blockIdx.y >= bs;
  int b = (int)blockIdx.y - (which ? bs : 0);
  const float* Wm = which ? Wk : Wq;
  const float* bias = which ? bk : bq;
  const float* X = (which ? ef : vf) + (size_t)b * C * N;
  u16* Ph = which ? Kh : Qh;
  u16* Pm = which ? Km : Qm;
  u16* Pl = which ? Kl : Ql;
  int n0 = blockIdx.x * 128;
  __shared__ float As[8][128];
  __shared__ float Xs[8][128];
  int tx = t & 15, ty = t >> 4;
  int ao = t >> 1, ac = (t & 1) * 4;
  int lk = t >> 5, lj = (t & 31) * 4;
  float acc[8][8] = {};
  for (int c0 = 0; c0 < C; c0 += 8) {
    __syncthreads();
    float4 wv = *(const float4*)&Wm[(size_t)ao * C + c0 + ac];
    As[ac + 0][ao] = wv.x; As[ac + 1][ao] = wv.y;
    As[ac + 2][ao] = wv.z; As[ac + 3][ao] = wv.w;
    *(float4*)&Xs[lk][lj] = *(const float4*)&X[(size_t)(c0 + lk) * N + n0 + lj];
    __syncthreads();
#pragma unroll
    for (int kk = 0; kk < 8; ++kk) {
      float a[8], bb[8];
      *(float4*)&a[0]  = *(const float4*)&As[kk][ty * 4];
      *(float4*)&a[4]  = *(const float4*)&As[kk][64 + ty * 4];
      *(float4*)&bb[0] = *(const float4*)&Xs[kk][tx * 4];
      *(float4*)&bb[4] = *(const float4*)&Xs[kk][64 + tx * 4];
#pragma unroll
      for (int i = 0; i < 8; ++i)
#pragma unroll
        for (int j = 0; j < 8; ++j)
          acc[i][j] = fmaf(a[i], bb[j], acc[i][j]);
    }
  }
  float bv[8];
#pragma unroll
  for (int i = 0; i < 8; ++i) bv[i] = bias[(i >> 2) * 64 + ty * 4 + (i & 3)];
#pragma unroll
  for (int j = 0; j < 8; ++j) {
    int n = n0 + tx * 4 + (j & 3) + (j >> 2) * 64;
    size_t nb = ((size_t)b * N + n) * C;
#pragma unroll
    for (int g = 0; g < 2; ++g) {
      int r0 = g * 64 + ty * 4;
      ushort4 hv, mv, lv;
      split3(acc[g * 4 + 0][j] + bv[g * 4 + 0], hv.x, mv.x, lv.x);
      split3(acc[g * 4 + 1][j] + bv[g * 4 + 1], hv.y, mv.y, lv.y);
      split3(acc[g * 4 + 2][j] + bv[g * 4 + 2], hv.z, mv.z, lv.z);
      split3(acc[g * 4 + 3][j] + bv[g * 4 + 3], hv.w, mv.w, lv.w);
      *(ushort4*)&Ph[nb + r0] = hv;
      *(ushort4*)&Pm[nb + r0] = mv;
      *(ushort4*)&Pl[nb + r0] = lv;
    }
  }
}

// ---------------- Pass B: score via MFMA bf16 3-split -----------------------
// R10: staging via __builtin_amdgcn_global_load_lds (16B/lane, no VGPR
// round-trip). LDS image identical to R7/R9: physical granule (row, pslot)
// holds global data (row, lslot = pslot ^ ((row>>1)&3)) — achieved with a
// LINEAR LDS dest (wave-uniform base + lane*16, m104 constraint) and the
// inverse-XOR applied to the per-lane GLOBAL source (m173 pattern).
// Per-lane global offsets are loop-invariant (+32 u16 per K-step).
// Compute phase / epilogue unchanged (reads via smoff XOR as before).
__device__ __forceinline__ int smoff(int a, int row, int slot) {
  return ((a * 128 + row) * 4 + (slot ^ ((row >> 1) & 3))) * 8;  // u16 units
}

__global__ __launch_bounds__(256) void att_mfma(
    const u16* __restrict__ Qh, const u16* __restrict__ Qm,
    const u16* __restrict__ Ql, const u16* __restrict__ Kh,
    const u16* __restrict__ Km, const u16* __restrict__ Kl,
    const float* __restrict__ H0, float* __restrict__ score,
    int C, int N, float rsdh) {
  int b = blockIdx.z;
  int o0 = blockIdx.y * 128, i0 = blockIdx.x * 128;
  __shared__ __align__(16) char smem_raw[6 * 128 * 32 * 2];  // 49152 B
  u16* smraw = (u16*)smem_raw;
  float (*et)[16][68] = (float(*)[16][68])smem_raw;  // aliased epilogue tile
  int t = threadIdx.x;
  int wave = t >> 6, lane = t & 63, quad = lane >> 4, lr = lane & 15;
  int wo = wave >> 1, wi = wave & 1;
  f32x4 acc[4][4];
#pragma unroll
  for (int mi = 0; mi < 4; ++mi)
#pragma unroll
    for (int ni = 0; ni < 4; ++ni) acc[mi][ni] = (f32x4){0.f, 0.f, 0.f, 0.f};

  // per-lane global source offsets (u16 units), loop-invariant
  int row0 = (wave << 5) + (lane >> 2);        // rows [32w, 32w+16)
  int row1 = row0 + 16;                        // rows [32w+16, 32w+32)
  int ls0 = (lane & 3) ^ ((row0 >> 1) & 3);    // inverse-swizzled source slot
  int ls1 = (lane & 3) ^ ((row1 >> 1) & 3);
  size_t offQ0 = ((size_t)b * N + o0 + row0) * C + ls0 * 8;
  size_t offQ1 = ((size_t)b * N + o0 + row1) * C + ls1 * 8;
  size_t offK0 = ((size_t)b * N + i0 + row0) * C + ls0 * 8;
  size_t offK1 = ((size_t)b * N + i0 + row1) * C + ls1 * 8;
  const u16* gq[3] = {Qh, Qm, Ql};
  const u16* gk[3] = {Kh, Km, Kl};
  // wave-uniform LDS bases (u16 units): array a, half i -> a*4096 + w*1024 + i*512
  int ldsw = wave << 10;

  for (int c0 = 0; c0 < C; c0 += 32) {
    __syncthreads();
#pragma unroll
    for (int a = 0; a < 3; ++a) {
      __builtin_amdgcn_global_load_lds(
          (const __attribute__((address_space(1))) void*)(gq[a] + offQ0 + c0),
          (__attribute__((address_space(3))) void*)&smraw[a * 4096 + ldsw],
          16, 0, 0);
      __builtin_amdgcn_global_load_lds(
          (const __attribute__((address_space(1))) void*)(gq[a] + offQ1 + c0),
          (__attribute__((address_space(3))) void*)&smraw[a * 4096 + ldsw + 512],
          16, 0, 0);
      __builtin_amdgcn_global_load_lds(
          (const __attribute__((address_space(1))) void*)(gk[a] + offK0 + c0),
          (__attribute__((address_space(3))) void*)&smraw[(3 + a) * 4096 + ldsw],
          16, 0, 0);
      __builtin_amdgcn_global_load_lds(
          (const __attribute__((address_space(1))) void*)(gk[a] + offK1 + c0),
          (__attribute__((address_space(3))) void*)&smraw[(3 + a) * 4096 + ldsw + 512],
          16, 0, 0);
    }
    __syncthreads();
    short8 bh[4], bm[4], bl[4];
#pragma unroll
    for (int ni = 0; ni < 4; ++ni) {
      int row = wi * 64 + ni * 16 + lr;
      bh[ni] = *(const short8*)&smraw[smoff(3, row, quad)];
      bm[ni] = *(const short8*)&smraw[smoff(4, row, quad)];
      bl[ni] = *(const short8*)&smraw[smoff(5, row, quad)];
    }
#pragma unroll
    for (int mi = 0; mi < 4; ++mi) {
      int row = wo * 64 + mi * 16 + lr;
      short8 ah = *(const short8*)&smraw[smoff(0, row, quad)];
      short8 am = *(const short8*)&smraw[smoff(1, row, quad)];
      short8 al = *(const short8*)&smraw[smoff(2, row, quad)];
#pragma unroll
      for (int ni = 0; ni < 4; ++ni) {
        f32x4 c = acc[mi][ni];
        c = __builtin_amdgcn_mfma_f32_16x16x32_bf16(ah, bl[ni], c, 0, 0, 0);
        c = __builtin_amdgcn_mfma_f32_16x16x32_bf16(al, bh[ni], c, 0, 0, 0);
        c = __builtin_amdgcn_mfma_f32_16x16x32_bf16(am, bm[ni], c, 0, 0, 0);
        c = __builtin_amdgcn_mfma_f32_16x16x32_bf16(ah, bm[ni], c, 0, 0, 0);
        c = __builtin_amdgcn_mfma_f32_16x16x32_bf16(am, bh[ni], c, 0, 0, 0);
        c = __builtin_amdgcn_mfma_f32_16x16x32_bf16(ah, bh[ni], c, 0, 0, 0);
        acc[mi][ni] = c;
      }
    }
  }
  __syncthreads();  // sm dead from here; et aliases its storage
  const float* Hb = H0 + (size_t)b * N * N;
  float* Sb = score + (size_t)b * N * N;
  int rr = lane >> 2, seg = lane & 3;
#pragma unroll
  for (int mi = 0; mi < 4; ++mi) {
#pragma unroll
    for (int ni = 0; ni < 4; ++ni)
#pragma unroll
      for (int r = 0; r < 4; ++r)
        et[wave][quad * 4 + r][ni * 16 + lr] = acc[mi][ni][r];
    __syncthreads();
    int o = o0 + wo * 64 + mi * 16 + rr;
    const float* hr = Hb + (size_t)o * N + i0 + wi * 64;
    float* sr = Sb + (size_t)o * N + i0 + wi * 64;
#pragma unroll
    for (int j = 0; j < 4; ++j) {
      int col = j * 16 + seg * 4;
      float4 c = *(const float4*)&et[wave][rr][col];
      float4 h = *(const float4*)&hr[col];
      float4 oV;
      oV.x = (h.x > 0.f) ? 1.f / (1.f + __expf(-c.x * rsdh)) : 0.f;
      oV.y = (h.y > 0.f) ? 1.f / (1.f + __expf(-c.y * rsdh)) : 0.f;
      oV.z = (h.z > 0.f) ? 1.f / (1.f + __expf(-c.z * rsdh)) : 0.f;
      oV.w = (h.w > 0.f) ? 1.f / (1.f + __expf(-c.w * rsdh)) : 0.f;
      *(float4*)&sr[col] = oV;
    }
    __syncthreads();  // et reused next mi
  }
}

// ---- Pass C (fused): per-row exact k-th largest + select from registers.
// R9-exact: ternary search, LDS column partials, global-atomic flush to
// degE/We (removes PE/PW round-trip), fused Dv rows.
template <int V4>
__global__ __launch_bounds__(512) void topk_select(
    float* __restrict__ scoreW, float* __restrict__ Hout,
    float* __restrict__ degV, float* __restrict__ Dv,
    float* __restrict__ degE, float* __restrict__ WeAcc,
    const int* __restrict__ itp, int N) {
  int b = blockIdx.y;
  int strip = blockIdx.x;
  int t = threadIdx.x;
  int wave = t >> 6, lane = t & 63;
  int row = strip * 8 + wave;
  size_t rowoff = ((size_t)b * N + row) * N;
  extern __shared__ float cols[];  // [2][N]: colE, colW
  float* colE = cols;
  float* colW = cols + N;
  for (int i = t; i < 2 * N; i += 512) cols[i] = 0.f;

  float4 v4[V4];
#pragma unroll
  for (int q = 0; q < V4; ++q)
    v4[q] = *(const float4*)(scoreW + rowoff + 4 * lane + (q << 8));
  int itv = *itp;
  int k = (int)floor((double)N * 0.1 * (double)(NUM_LAYER - 1 - itv) + 0.5);
  unsigned lo = 0u, hi = 0x3F800000u;  // scores in [0, 1]
  while (lo < hi) {
    unsigned r = hi - lo;
    unsigned p1 = lo + (r + 2u) / 3u;          // >= lo+1
    unsigned p2 = lo + (2u * r + 2u) / 3u;     // p1 <= p2 <= hi
    float t1 = __uint_as_float(p1), t2 = __uint_as_float(p2);
    int c = 0;
#pragma unroll
    for (int q = 0; q < V4; ++q) {
      c += (v4[q].x >= t1) ? 1 : 0; c += (v4[q].x >= t2) ? 0x10000 : 0;
      c += (v4[q].y >= t1) ? 1 : 0; c += (v4[q].y >= t2) ? 0x10000 : 0;
      c += (v4[q].z >= t1) ? 1 : 0; c += (v4[q].z >= t2) ? 0x10000 : 0;
      c += (v4[q].w >= t1) ? 1 : 0; c += (v4[q].w >= t2) ? 0x10000 : 0;
    }
#pragma unroll
    for (int off = 1; off < 64; off <<= 1) c += __shfl_xor(c, off);
    int c2 = c >> 16, c1 = c & 0xFFFF;
    if (c2 >= k) lo = p2;
    else if (c1 >= k) { lo = p1; hi = p2 - 1u; }
    else hi = p1 - 1u;
  }
  float am = __uint_as_float(lo);  // uniform across wave
  __syncthreads();                 // cols[] zeroed

  float rs = 0.f;
#pragma unroll
  for (int q = 0; q < V4; ++q) {
    int c0 = 4 * lane + (q << 8);
    float4 s = v4[q];
    float4 w, h;
    w.x = (s.x >= am) ? s.x : 0.f; h.x = (w.x > 0.f) ? 1.f : 0.f;
    w.y = (s.y >= am) ? s.y : 0.f; h.y = (w.y > 0.f) ? 1.f : 0.f;
    w.z = (s.z >= am) ? s.z : 0.f; h.z = (w.z > 0.f) ? 1.f : 0.f;
    w.w = (s.w >= am) ? s.w : 0.f; h.w = (w.w > 0.f) ? 1.f : 0.f;
    *(float4*)(scoreW + rowoff + c0) = w;
    *(float4*)(Hout + rowoff + c0) = h;
    rs += h.x + h.y + h.z + h.w;
    if (h.x != 0.f) { atomicAdd(&colE[c0 + 0], 1.f); atomicAdd(&colW[c0 + 0], w.x); }
    if (h.y != 0.f) { atomicAdd(&colE[c0 + 1], 1.f); atomicAdd(&colW[c0 + 1], w.y); }
    if (h.z != 0.f) { atomicAdd(&colE[c0 + 2], 1.f); atomicAdd(&colW[c0 + 2], w.z); }
    if (h.w != 0.f) { atomicAdd(&colE[c0 + 3], 1.f); atomicAdd(&colW[c0 + 3], w.w); }
  }
#pragma unroll
  for (int off = 32; off; off >>= 1) rs += __shfl_down(rs, off);
  float rsb = __shfl(rs, 0);
  if (lane == 0) degV[b * N + row] = rsb;
  {
    // fused Dv row: zeros + 1/degV on the diagonal (row owned by this wave)
    float inv = (rsb != 0.f) ? 1.f / rsb : 0.f;
    float* dvr = Dv + ((size_t)b * N + row) * N;
    for (int c4 = lane * 4; c4 < N; c4 += 256) {
      float4 z = {0.f, 0.f, 0.f, 0.f};
      unsigned dd = (unsigned)(row - c4);
      if (dd < 4u) ((float*)&z)[dd] = inv;
      *(float4*)&dvr[c4] = z;
    }
  }
  __syncthreads();
  // flush nonzero column partials with global atomics (degE exact: integer
  // counts in fp32; We reassociation ~1e-5 abs, far inside tolerance)
  for (int c = t; c < 2 * N; c += 512) {
    float v = cols[c];
    if (v != 0.f) {
      if (c < N) atomicAdd(&degE[b * N + c], v);
      else       atomicAdd(&WeAcc[b * N + c - N], v);
    }
  }
}

// ------- Pass E: streaming fill of De (zeros + 1/degE diagonal) -------
__global__ __launch_bounds__(256) void de_fill(
    float* __restrict__ De, const float* __restrict__ degE, int N) {
  int b = blockIdx.y;
  int r0 = blockIdx.x * 8;
  float* out = De + (size_t)b * N * N;
  const float* deg = degE + b * N;
  int t = threadIdx.x;
#pragma unroll
  for (int r = r0; r < r0 + 8; ++r) {
    float d = deg[r];
    float inv = (d != 0.f) ? 1.f / d : 0.f;
    size_t rowoff = (size_t)r * N;
    for (int c4 = t * 4; c4 < N; c4 += 1024) {
      float4 v = {0.f, 0.f, 0.f, 0.f};
      unsigned dd = (unsigned)(r - c4);
      if (dd < 4u) ((float*)&v)[dd] = inv;
      *(float4*)&out[rowoff + c4] = v;
    }
  }
}

// ---------------- Pass F: W_edge normalize ----------------
__global__ __launch_bounds__(256) void wedge_norm(
    const float* __restrict__ We, float* __restrict__ out, int N) {
  int b = blockIdx.x;
  int t = threadIdx.x;
  const float* w = We + (size_t)b * N;
  float ss = 0.f;
  for (int i = t; i < N; i += 256) { float x = w[i]; ss += x * x; }
  for (int off = 32; off; off >>= 1) ss += __shfl_down(ss, off);
  __shared__ float p[4];
  if ((t & 63) == 0) p[t >> 6] = ss;
  __syncthreads();
  float tot = p[0] + p[1] + p[2] + p[3];
  float nrm = fmaxf(sqrtf(tot), 1e-12f);
  for (int i = t; i < N; i += 256) out[(size_t)b * N + i] = w[i] / nrm;
}

extern "C" void kernel_launch(void* const* d_in, const int* in_sizes, int n_in,
                              void* d_out, int out_size, void* d_ws, size_t ws_size,
                              hipStream_t stream) {
  const float* H0 = (const float*)d_in[0];
  const float* vf = (const float*)d_in[1];
  const float* ef = (const float*)d_in[2];
  const float* Wq = (const float*)d_in[3];
  const float* bq = (const float*)d_in[4];
  const float* Wk = (const float*)d_in[5];
  const float* bk = (const float*)d_in[6];
  const int* itp  = (const int*)d_in[7];

  int C = (int)(sqrt((double)in_sizes[3]) + 0.5);          // 128
  long long ratio = (long long)in_sizes[0] / in_sizes[1];  // N/C
  int N = (int)(C * ratio);                                // 2048
  int bs = (int)(in_sizes[1] / ((long long)C * N));        // 8
  size_t bNN = (size_t)bs * N * N;
  size_t bNC = (size_t)bs * N * C;
  int S = N >> 3;                                          // 8-row strips

  float* outH  = (float*)d_out;
  float* outW  = outH + bNN;
  float* outDe = outW + bNN;
  float* outDv = outDe + bNN;
  float* outWe = outDv + bNN;

  size_t bsN = (size_t)bs * N;
  float* degE = (float*)d_ws;   // zero-init'd in pass A prologue
  float* degV = degE + bsN;
  float* We   = degV + bsN;
  u16* splits;   // 6 arrays of bNC u16 each
  size_t need = 3 * bsN * sizeof(float) + 6 * bNC * sizeof(u16);
  if (ws_size >= need) {
    splits = (u16*)(We + bsN);
  } else {
    // outDe dead until de_fill (after topk_select) — safe scratch.
    splits = (u16*)outDe;
  }
  u16* Qh = splits;
  u16* Qm = Qh + bNC;
  u16* Ql = Qm + bNC;
  u16* Kh = Ql + bNC;
  u16* Km = Kh + bNC;
  u16* Kl = Km + bNC;

  float rsdh = (float)(1.0 / sqrt((double)C));  // NUM_HEADS==1 -> dh=C
  size_t colsBytes = 2 * (size_t)N * sizeof(float);
  int zcount = (int)(3 * bsN);  // degE, degV, We contiguous

  qk_gemm_split<<<dim3(N / 128, 2 * bs), 256, 0, stream>>>(
      Wq, bq, vf, Wk, bk, ef, Qh, Qm, Ql, Kh, Km, Kl, degE, zcount, C, N, bs);
  att_mfma<<<dim3(N / 128, N / 128, bs), 256, 0, stream>>>(
      Qh, Qm, Ql, Kh, Km, Kl, H0, outW, C, N, rsdh);
  if (N == 2048)
    topk_select<8><<<dim3(S, bs), 512, colsBytes, stream>>>(
        outW, outH, degV, outDv, degE, We, itp, N);
  else if (N == 1024)
    topk_select<4><<<dim3(S, bs), 512, colsBytes, stream>>>(
        outW, outH, degV, outDv, degE, We, itp, N);
  else  // N == 4096
    topk_select<16><<<dim3(S, bs), 512, colsBytes, stream>>>(
        outW, outH, degV, outDv, degE, We, itp, N);
  de_fill<<<dim3(N / 8, bs), 256, 0, stream>>>(outDe, degE, N);
  wedge_norm<<<dim3(bs), 256, 0, stream>>>(We, outWe, N);
}